// Round 5
// baseline (158.399 us; speedup 1.0000x reference)
//
#include <hip/hip_runtime.h>
#include <hip/hip_fp16.h>
#include <math.h>

#define Bv 4096
#define Sv 64
#define Ev 128
#define Hv 256
#define Cv 18
#define Mrows 16
#define WRDS 3072    // words per step buffer: emb kb0-3 (0..1023), h kb4-11 (1024..3071)

typedef _Float16 hfrag __attribute__((ext_vector_type(8)));
using f4v = __attribute__((ext_vector_type(4))) float;

#define LO_SCALE 2048.0f            // 2^11 on w1_lo (FC1 only)
#define LO_DESCALE (1.0f / 2048.0f)

// XOR swizzle: flips bits 2-4 by a hash of higher bits. Bits 0-1 preserved
// -> b64/b128 contiguity kept (16B-aligned chunks stay 16B-aligned).
__device__ inline int SW(int o) {
    return o ^ ((((o >> 5) ^ (o >> 8)) & 7) << 2);
}

__device__ inline float fast_tanh(float x) {
    // tanh(x) = 1 - 2/(exp2(2x*log2e)+1)
    float e = __builtin_amdgcn_exp2f(x * 2.8853900817779268f);
    return 1.0f - 2.0f * __builtin_amdgcn_rcpf(e + 1.0f);
}

__device__ inline unsigned pk_h2(float a, float b) {
    unsigned ua = __half_as_ushort(__float2half_rn(a));
    unsigned ub = __half_as_ushort(__float2half_rn(b));
    return ua | (ub << 16);
}

// ---- kernel A: build MFMA weight fragments + f16 embedding table ----
__global__ void build_frags(const float* __restrict__ W_ih,
                            const float* __restrict__ W_hh,
                            const float* __restrict__ W1,
                            const float* __restrict__ emb,
                            unsigned* __restrict__ wfh,
                            unsigned* __restrict__ wf1h, unsigned* __restrict__ wf1l,
                            unsigned* __restrict__ emb16w) {
    if (blockIdx.x >= 80) {
        int i = (blockIdx.x - 80) * 256 + threadIdx.x;   // 0..159999
        float4 a = *(const float4*)&emb[(size_t)i * 8];
        float4 b = *(const float4*)&emb[(size_t)i * 8 + 4];
        uint4 o;
        o.x = pk_h2(a.x, a.y); o.y = pk_h2(a.z, a.w);
        o.z = pk_h2(b.x, b.y); o.w = pk_h2(b.z, b.w);
        *reinterpret_cast<uint4*>(&emb16w[(size_t)i * 4]) = o;
        return;
    }
    int f = blockIdx.x * 256 + threadIdx.x;   // 0..20479
    bool isrnn = f < 12288;
    int g = isrnn ? f : f - 12288;
    int lane = g & 63, tile = (g >> 6) & 15, kb = g >> 10;
    int q = lane >> 4, col = lane & 15;
    int n = tile * 16 + col;
    unsigned hu[8], lu[8];
    #pragma unroll
    for (int j = 0; j < 8; ++j) {
        int k = kb * 32 + q * 8 + j;
        float x;
        if (isrnn) x = (k < Ev) ? W_ih[n * Ev + k] : W_hh[n * Hv + (k - Ev)];
        else       x = W1[n * Hv + k];
        __half h = __float2half_rn(x);
        hu[j] = __half_as_ushort(h);
        float l = (x - __half2float(h)) * LO_SCALE;
        lu[j] = __half_as_ushort(__float2half_rn(l));
    }
    unsigned* oh = (isrnn ? wfh : wf1h) + (size_t)g * 4;
    #pragma unroll
    for (int d = 0; d < 4; ++d) oh[d] = hu[2 * d] | (hu[2 * d + 1] << 16);
    if (!isrnn) {
        unsigned* ol = wf1l + (size_t)g * 4;
        #pragma unroll
        for (int d = 0; d < 4; ++d) ol[d] = lu[2 * d] | (lu[2 * d + 1] << 16);
    }
}

// ---- kernel B: fused recurrence + FC head; 4 waves x 4 N-tiles, W pinned ----
// LDS A-fragment traffic halves vs 8x2 (48 vs 96 ds_read_b128/CU/step, the
// former binding resource); MFMA per SIMD unchanged. 1 wave/SIMD -> full
// 512-reg unified file for the 192 weight VGPRs (launch_bounds(256,1)).
__global__ __launch_bounds__(256, 1) void rnn_fused(
    const int* __restrict__ x_in, const int* __restrict__ x_len,
    const unsigned short* __restrict__ emb16,
    const unsigned* __restrict__ wfh,
    const unsigned* __restrict__ wf1h, const unsigned* __restrict__ wf1l,
    const float* __restrict__ b_ih, const float* __restrict__ b_hh,
    const float* __restrict__ b1, const float* __restrict__ W2,
    const float* __restrict__ b2, float* __restrict__ out)
{
    __shared__ unsigned SH[2 * WRDS];   // 24 KB step buffers (f16 A fragments)
    __shared__ unsigned LF[2048];       // 8 KB last-h fragments
    float* yb = reinterpret_cast<float*>(SH);
    char* SHb = reinterpret_cast<char*>(SH);

    const int tid = threadIdx.x;
    const int lane = tid & 63, w = tid >> 6;     // wave 0..3
    const int q = lane >> 4, col = lane & 15;
    const int rb = blockIdx.x * Mrows;

    // resident W: tiles 4w..4w+3 -> f16 hi all 12 kb (192 regs)
    hfrag wh[4][12];
    #pragma unroll
    for (int i = 0; i < 4; ++i) {
        const int ti = 4 * w + i;
        #pragma unroll
        for (int kb = 0; kb < 12; ++kb) {
            int fid = (kb * 16 + ti) * 64 + lane;
            wh[i][kb] = *reinterpret_cast<const hfrag*>(&wfh[(size_t)fid * 4]);
        }
    }
    #pragma unroll
    for (int i = 0; i < 4; ++i)
        #pragma unroll
        for (int kb = 0; kb < 12; ++kb) asm volatile("" : "+v"(wh[i][kb]));

    // bias folded into MFMA C-init of the even chains
    f4v bcv[4];
    #pragma unroll
    for (int i = 0; i < 4; ++i)
        #pragma unroll
        for (int r = 0; r < 4; ++r) {
            int n = (4 * w + i) * 16 + 4 * q + r;
            bcv[i][r] = b_ih[n] + b_hh[n];
        }
    const int len_c = x_len[rb + col];
    int tmax = len_c;
    #pragma unroll
    for (int m = 1; m < 16; m <<= 1) {
        int o = __shfl_xor(tmax, m, 64);
        tmax = tmax > o ? tmax : o;
    }

    // precomputed swizzled LDS BYTE offsets (loop-invariant registers)
    int abyte[12];                      // A-fragment reads, kb 0..11
    #pragma unroll
    for (int kb = 0; kb < 12; ++kb) abyte[kb] = SW(kb * 256 + lane * 4) * 4;
    int wbyte[4];                       // h-fragment writes (4 tiles)
    #pragma unroll
    for (int i = 0; i < 4; ++i) {
        const int ti = 4 * w + i;
        const int dl = ((ti & 1) * 2 + (q >> 1)) * 16 + col;
        wbyte[i] = SW((4 + (ti >> 1)) * 256 + dl * 4 + (q & 1) * 2) * 4;
    }
    // emb staging: thread = (row em, 16B-chunk kt): copies 16 B per step
    const int em = tid >> 4;            // row 0..15
    const int kt = tid & 15;            // 16B chunk 0..15 (k0 = 8*kt)
    const int ebyte = SW((kt >> 2) * 256 + (kt & 3) * 64 + em * 4) * 4;
    const int* xrow = x_in + (size_t)(rb + em) * Sv;
    const char* embB = reinterpret_cast<const char*>(emb16);
    const int ekoff = kt * 16;          // byte offset within 256 B emb16 row

    // zero h region of buffer 0 (words 1024..3071; SW permutes within)
    for (int u = tid; u < 2048; u += 256) SH[1024 + u] = 0u;

    // prologue: stage emb(0) -> buf0; preload row 1 (depth-2 pipeline)
    {
        uint4 e0 = *reinterpret_cast<const uint4*>(embB + ((unsigned)xrow[0] << 8) + ekoff);
        *reinterpret_cast<uint4*>(SHb + ebyte) = e0;
    }
    uint4 ev_cur = *reinterpret_cast<const uint4*>(embB + ((unsigned)xrow[1] << 8) + ekoff);
    uint2 snap[4];
    #pragma unroll
    for (int i = 0; i < 4; ++i) snap[i] = make_uint2(0u, 0u);
    __syncthreads();

    f4v zf = {0.f, 0.f, 0.f, 0.f};

    // One step: read A-fragments at byte offset RBb, write h(t)/emb(t+1) at WBb.
#define STEPX(RBb, WBb, TT)                                                        \
    {                                                                              \
        int tn = (TT) + 2; tn = tn > 63 ? 63 : tn;                                 \
        uint4 ev_next = *reinterpret_cast<const uint4*>(                           \
            embB + ((unsigned)xrow[tn] << 8) + ekoff);                             \
        f4v aE[4], aO[4];                                                          \
        _Pragma("unroll")                                                          \
        for (int i = 0; i < 4; ++i) { aE[i] = bcv[i]; aO[i] = zf; }                \
        _Pragma("unroll")                                                          \
        for (int kb = 0; kb < 12; ++kb) {                                          \
            hfrag ah = *reinterpret_cast<const hfrag*>(SHb + abyte[kb] + (RBb));   \
            if (kb & 1) {                                                          \
                _Pragma("unroll")                                                  \
                for (int i = 0; i < 4; ++i)                                        \
                    aO[i] = __builtin_amdgcn_mfma_f32_16x16x32_f16(wh[i][kb], ah, aO[i], 0, 0, 0); \
            } else {                                                               \
                _Pragma("unroll")                                                  \
                for (int i = 0; i < 4; ++i)                                        \
                    aE[i] = __builtin_amdgcn_mfma_f32_16x16x32_f16(wh[i][kb], ah, aE[i], 0, 0, 0); \
            }                                                                      \
        }                                                                          \
        *reinterpret_cast<uint4*>(SHb + ebyte + (WBb)) = ev_cur;                   \
        _Pragma("unroll")                                                          \
        for (int i = 0; i < 4; ++i) {                                              \
            f4v s = aE[i] + aO[i];                                                 \
            float h0 = fast_tanh(s[0]), h1 = fast_tanh(s[1]);                      \
            float h2 = fast_tanh(s[2]), h3 = fast_tanh(s[3]);                      \
            uint2 hu = make_uint2(pk_h2(h0, h1), pk_h2(h2, h3));                   \
            *reinterpret_cast<uint2*>(SHb + wbyte[i] + (WBb)) = hu;                \
            if ((TT) == len_c - 1) snap[i] = hu;                                   \
        }                                                                          \
        ev_cur = ev_next;                                                          \
        asm volatile("s_waitcnt lgkmcnt(0)" ::: "memory");                         \
        __builtin_amdgcn_s_barrier();                                              \
        asm volatile("" ::: "memory");                                             \
    }

    // unroll x2: buffer parity is a compile-time byte offset (0 / 12288).
    // odd tmax runs one harmless extra step (snap is exact-match guarded).
    #pragma unroll 1
    for (int t = 0; t < tmax; t += 2) {
        STEPX(0, 12288, t)
        STEPX(12288, 0, t + 1)
    }
#undef STEPX

    // ---- write last-h snapshots to LF (same swizzled pattern, minus 1024w) ----
    #pragma unroll
    for (int i = 0; i < 4; ++i) {
        const int ti = 4 * w + i;
        const int dl = ((ti & 1) * 2 + (q >> 1)) * 16 + col;
        *reinterpret_cast<uint2*>(&LF[SW((ti >> 1) * 256 + dl * 4 + (q & 1) * 2)]) = snap[i];
    }
    __syncthreads();

    // ---- fused FC1 (MFMA, f16 hi+lo) on LF; wave w -> tiles 4w..4w+3 ----
    f4v fH[4], fL[4];
    #pragma unroll
    for (int i = 0; i < 4; ++i) {
        float4 bb = *(const float4*)&b1[(4 * w + i) * 16 + 4 * q];
        fH[i] = (f4v){bb.x, bb.y, bb.z, bb.w};
        fL[i] = zf;
    }
    #pragma unroll
    for (int kb = 0; kb < 8; ++kb) {
        hfrag ah = *reinterpret_cast<const hfrag*>(&LF[SW(kb * 256 + lane * 4)]);
        #pragma unroll
        for (int i = 0; i < 4; ++i) {
            int fid = (kb * 16 + 4 * w + i) * 64 + lane;
            hfrag w0h = *reinterpret_cast<const hfrag*>(&wf1h[(size_t)fid * 4]);
            hfrag w0l = *reinterpret_cast<const hfrag*>(&wf1l[(size_t)fid * 4]);
            fH[i] = __builtin_amdgcn_mfma_f32_16x16x32_f16(w0h, ah, fH[i], 0, 0, 0);
            fL[i] = __builtin_amdgcn_mfma_f32_16x16x32_f16(w0l, ah, fL[i], 0, 0, 0);
        }
    }

    // y = relu(...) into yb (aliases SH; step buffers dead, LF untouched)
    #pragma unroll
    for (int i = 0; i < 4; ++i) {
        int n0 = (4 * w + i) * 16 + 4 * q;
        float4 yv;
        yv.x = fmaxf(fH[i][0] + fL[i][0] * LO_DESCALE, 0.f);
        yv.y = fmaxf(fH[i][1] + fL[i][1] * LO_DESCALE, 0.f);
        yv.z = fmaxf(fH[i][2] + fL[i][2] * LO_DESCALE, 0.f);
        yv.w = fmaxf(fH[i][3] + fL[i][3] * LO_DESCALE, 0.f);
        *reinterpret_cast<float4*>(&yb[col * 260 + n0]) = yv;
    }
    __syncthreads();

    // ---- FC2: 16 x 18 dots of length 256 (288 items on 256 threads) ----
    for (int it = tid; it < Mrows * Cv; it += 256) {
        int r = it & 15, cc = it >> 4;
        float s = b2[cc];
        #pragma unroll 8
        for (int k4 = 0; k4 < Hv / 4; ++k4) {
            float4 yv = *reinterpret_cast<const float4*>(&yb[r * 260 + 4 * k4]);
            float4 wv2 = *(const float4*)&W2[cc * Hv + 4 * k4];
            s = fmaf(yv.x, wv2.x, s);
            s = fmaf(yv.y, wv2.y, s);
            s = fmaf(yv.z, wv2.z, s);
            s = fmaf(yv.w, wv2.w, s);
        }
        out[(rb + r) * Cv + cc] = s;
    }
}

extern "C" void kernel_launch(void* const* d_in, const int* in_sizes, int n_in,
                              void* d_out, int out_size, void* d_ws, size_t ws_size,
                              hipStream_t stream) {
    const int*   x_in  = (const int*)  d_in[0];
    const int*   x_len = (const int*)  d_in[1];
    const float* emb   = (const float*)d_in[2];
    const float* W_ih  = (const float*)d_in[3];
    const float* W_hh  = (const float*)d_in[4];
    const float* b_ih  = (const float*)d_in[5];
    const float* b_hh  = (const float*)d_in[6];
    const float* W1    = (const float*)d_in[7];
    const float* b1    = (const float*)d_in[8];
    const float* W2    = (const float*)d_in[9];
    const float* b2    = (const float*)d_in[10];
    float* out = (float*)d_out;

    unsigned* wfh    = (unsigned*)d_ws;          // 12288 frags * 16 B
    unsigned* wf1h   = wfh  + 12288 * 4;         // 8192 * 16 B
    unsigned* wf1l   = wf1h + 8192 * 4;          // 8192 * 16 B
    unsigned* emb16w = wf1l + 8192 * 4;          // 10000*128 f16 = 2.56 MB

    build_frags<<<705, 256, 0, stream>>>(W_ih, W_hh, W1, emb,
                                         wfh, wf1h, wf1l, emb16w);
    rnn_fused<<<Bv / Mrows, 256, 0, stream>>>(x_in, x_len,
                                              (const unsigned short*)emb16w,
                                              wfh, wf1h, wf1l, b_ih, b_hh,
                                              b1, W2, b2, out);
}

// Round 7
// 138.585 us; speedup vs baseline: 1.1430x; 1.1430x over previous
//
#include <hip/hip_runtime.h>
#include <hip/hip_fp16.h>
#include <math.h>

#define Bv 4096
#define Sv 64
#define Ev 128
#define Hv 256
#define Cv 18
#define Mrows 16

typedef _Float16 hfrag __attribute__((ext_vector_type(8)));
using f4v = __attribute__((ext_vector_type(4))) float;

#define LO_SCALE 2048.0f            // 2^11 on w1_lo (FC1 only)
#define LO_DESCALE (1.0f / 2048.0f)

// XOR swizzle: flips bits 2-4 by a hash of higher bits. Bits 0-1 preserved
// -> b64/b128 contiguity kept. Applied to buffer-relative WORD offsets;
// write and read sides use the same mapping (bijective per 2048-word region).
__device__ inline int SW(int o) {
    return o ^ ((((o >> 5) ^ (o >> 8)) & 7) << 2);
}

__device__ inline float fast_tanh(float x) {
    // tanh(x) = 1 - 2/(exp2(2x*log2e)+1)
    float e = __builtin_amdgcn_exp2f(x * 2.8853900817779268f);
    return 1.0f - 2.0f * __builtin_amdgcn_rcpf(e + 1.0f);
}

__device__ inline unsigned pk_h2(float a, float b) {
    unsigned ua = __half_as_ushort(__float2half_rn(a));
    unsigned ub = __half_as_ushort(__float2half_rn(b));
    return ua | (ub << 16);
}

// ---- kernel A: build MFMA weight fragments + f16 embedding table ----
__global__ void build_frags(const float* __restrict__ W_ih,
                            const float* __restrict__ W_hh,
                            const float* __restrict__ W1,
                            const float* __restrict__ emb,
                            unsigned* __restrict__ wfh,
                            unsigned* __restrict__ wf1h, unsigned* __restrict__ wf1l,
                            unsigned* __restrict__ emb16w) {
    if (blockIdx.x >= 80) {
        int i = (blockIdx.x - 80) * 256 + threadIdx.x;   // 0..159999
        float4 a = *(const float4*)&emb[(size_t)i * 8];
        float4 b = *(const float4*)&emb[(size_t)i * 8 + 4];
        uint4 o;
        o.x = pk_h2(a.x, a.y); o.y = pk_h2(a.z, a.w);
        o.z = pk_h2(b.x, b.y); o.w = pk_h2(b.z, b.w);
        *reinterpret_cast<uint4*>(&emb16w[(size_t)i * 4]) = o;
        return;
    }
    int f = blockIdx.x * 256 + threadIdx.x;   // 0..20479
    bool isrnn = f < 12288;
    int g = isrnn ? f : f - 12288;
    int lane = g & 63, tile = (g >> 6) & 15, kb = g >> 10;
    int q = lane >> 4, col = lane & 15;
    int n = tile * 16 + col;
    unsigned hu[8], lu[8];
    #pragma unroll
    for (int j = 0; j < 8; ++j) {
        int k = kb * 32 + q * 8 + j;
        float x;
        if (isrnn) x = (k < Ev) ? W_ih[n * Ev + k] : W_hh[n * Hv + (k - Ev)];
        else       x = W1[n * Hv + k];
        __half h = __float2half_rn(x);
        hu[j] = __half_as_ushort(h);
        float l = (x - __half2float(h)) * LO_SCALE;
        lu[j] = __half_as_ushort(__float2half_rn(l));
    }
    unsigned* oh = (isrnn ? wfh : wf1h) + (size_t)g * 4;
    #pragma unroll
    for (int d = 0; d < 4; ++d) oh[d] = hu[2 * d] | (hu[2 * d + 1] << 16);
    if (!isrnn) {
        unsigned* ol = wf1l + (size_t)g * 4;
        #pragma unroll
        for (int d = 0; d < 4; ++d) ol[d] = lu[2 * d] | (lu[2 * d + 1] << 16);
    }
}

// ---- kernel B: fused recurrence + FC head; 8 waves x 2 N-tiles (R4 best) ----
// New vs R4: emb fragments for step t+1 are ds_read into REGISTERS during
// step t (from a separate emb double-buffer staged 2 steps ahead), so the
// post-barrier critical path is only the 8 h ds_reads (64/CU vs 96/CU) and
// the 4 emb MFMAs issue immediately from regs, covering h-read latency.
// LDS map (bytes): h dbuf 0/8192 (8 kb x 1 KB each); emb dbuf 16384 + 0/4096.
__global__ __launch_bounds__(512, 2) void rnn_fused(
    const int* __restrict__ x_in, const int* __restrict__ x_len,
    const unsigned short* __restrict__ emb16,
    const unsigned* __restrict__ wfh,
    const unsigned* __restrict__ wf1h, const unsigned* __restrict__ wf1l,
    const float* __restrict__ b_ih, const float* __restrict__ b_hh,
    const float* __restrict__ b1, const float* __restrict__ W2,
    const float* __restrict__ b2, float* __restrict__ out)
{
    __shared__ unsigned SH[6144];   // 24 KB: h dbuf (0..4095) + emb dbuf (4096..6143)
    __shared__ unsigned LF[2048];   // 8 KB last-h fragments
    float* yb = reinterpret_cast<float*>(SH);   // fc y buffer aliases SH after loop
    char* SHb = reinterpret_cast<char*>(SH);

    const int tid = threadIdx.x;
    const int lane = tid & 63, w = tid >> 6;     // wave 0..7
    const int q = lane >> 4, col = lane & 15;
    const int rb = blockIdx.x * Mrows;

    // resident W: tiles 2w, 2w+1 -> f16 hi all 12 kb (96 regs)
    hfrag wh[2][12];
    #pragma unroll
    for (int i = 0; i < 2; ++i) {
        const int ti = 2 * w + i;
        #pragma unroll
        for (int kb = 0; kb < 12; ++kb) {
            int fid = (kb * 16 + ti) * 64 + lane;
            wh[i][kb] = *reinterpret_cast<const hfrag*>(&wfh[(size_t)fid * 4]);
        }
    }
    #pragma unroll
    for (int i = 0; i < 2; ++i)
        #pragma unroll
        for (int kb = 0; kb < 12; ++kb) asm volatile("" : "+v"(wh[i][kb]));

    // bias folded into MFMA C-init of the even chains
    f4v bcv0, bcv1;
    #pragma unroll
    for (int r = 0; r < 4; ++r) {
        bcv0[r] = b_ih[(2 * w) * 16 + 4 * q + r] + b_hh[(2 * w) * 16 + 4 * q + r];
        bcv1[r] = b_ih[(2 * w + 1) * 16 + 4 * q + r] + b_hh[(2 * w + 1) * 16 + 4 * q + r];
    }
    const int len_c = x_len[rb + col];
    int tmax = len_c;
    #pragma unroll
    for (int m = 1; m < 16; m <<= 1) {
        int o = __shfl_xor(tmax, m, 64);
        tmax = tmax > o ? tmax : o;
    }

    // precomputed swizzled LDS BYTE offsets (loop-invariant registers)
    int hbyte[8];                       // h A-fragment reads, h-kb 0..7
    #pragma unroll
    for (int hb = 0; hb < 8; ++hb) hbyte[hb] = SW(hb * 256 + lane * 4) * 4;
    int ebr[4];                         // emb A-fragment reads, kb 0..3
    #pragma unroll
    for (int kb = 0; kb < 4; ++kb) ebr[kb] = SW(kb * 256 + lane * 4) * 4;
    int wbyte[2];                       // h-fragment writes (2 tiles)
    #pragma unroll
    for (int i = 0; i < 2; ++i) {
        const int ti = 2 * w + i;
        const int dl = ((ti & 1) * 2 + (q >> 1)) * 16 + col;
        wbyte[i] = SW((ti >> 1) * 256 + dl * 4 + (q & 1) * 2) * 4;
    }
    // emb staging: thread = (row em, 8B-chunk kt): copies 8 B (4 halves)
    const int em = tid >> 5;            // row 0..15
    const int kt = tid & 31;            // 8B chunk 0..31
    const int es = SW((kt >> 3) * 256 + (((kt >> 1) & 3) * 16 + em) * 4 + (kt & 1) * 2) * 4;
    const int* xrow = x_in + (size_t)(rb + em) * Sv;
    const char* embB = reinterpret_cast<const char*>(emb16);
    const int ekoff = kt * 8;           // byte offset within 256 B emb16 row

    // zero h buffer 0 (bytes 0..8191)
    for (int u = tid; u < 2048; u += 512) SH[u] = 0u;

    // prologue: stage emb(0)->ebuf0, emb(1)->ebuf1; evA = row 2
    {
        uint2 e0 = *reinterpret_cast<const uint2*>(embB + ((unsigned)xrow[0] << 8) + ekoff);
        uint2 e1 = *reinterpret_cast<const uint2*>(embB + ((unsigned)xrow[1] << 8) + ekoff);
        *reinterpret_cast<uint2*>(SHb + 16384 + es) = e0;
        *reinterpret_cast<uint2*>(SHb + 16384 + 4096 + es) = e1;
    }
    uint2 evA = *reinterpret_cast<const uint2*>(embB + ((unsigned)xrow[2] << 8) + ekoff);
    uint2 evB;
    uint2 snap[2];
    snap[0] = snap[1] = make_uint2(0u, 0u);
    __syncthreads();

    // read emb(0) fragments into regs (efA); second barrier so all waves'
    // reads complete before step 0 overwrites ebuf0 with emb(2)
    hfrag efA0, efA1, efA2, efA3, efB0, efB1, efB2, efB3;
    efA0 = *reinterpret_cast<const hfrag*>(SHb + 16384 + ebr[0]);
    efA1 = *reinterpret_cast<const hfrag*>(SHb + 16384 + ebr[1]);
    efA2 = *reinterpret_cast<const hfrag*>(SHb + 16384 + ebr[2]);
    efA3 = *reinterpret_cast<const hfrag*>(SHb + 16384 + ebr[3]);
    __syncthreads();

    f4v zf = {0.f, 0.f, 0.f, 0.f};

    // One step t: h read parity HR (t&1), h write parity HW ((t+1)&1);
    // emb reg frags EFC (emb(t)); read emb(t+1) -> EFN from parity ER
    // ((t+1)&1); stage emb(t+2)=EVS to parity EW (t&1); load EVL=row t+3.
#define STEPX(HR, HW, ER, EW, EFC0,EFC1,EFC2,EFC3, EFN0,EFN1,EFN2,EFN3, EVS, EVL, TT) \
    {                                                                              \
        int tn = (TT) + 3; tn = tn > 63 ? 63 : tn;                                 \
        EVL = *reinterpret_cast<const uint2*>(embB + ((unsigned)xrow[tn] << 8) + ekoff); \
        hfrag ah[8];                                                               \
        _Pragma("unroll")                                                          \
        for (int hb = 0; hb < 8; ++hb)                                             \
            ah[hb] = *reinterpret_cast<const hfrag*>(SHb + hbyte[hb] + (HR));      \
        f4v aE0 = bcv0, aE1 = bcv1, aO0 = zf, aO1 = zf;                            \
        /* emb MFMAs: operands already in regs, issue immediately */               \
        aE0 = __builtin_amdgcn_mfma_f32_16x16x32_f16(wh[0][0], EFC0, aE0, 0, 0, 0); \
        aE1 = __builtin_amdgcn_mfma_f32_16x16x32_f16(wh[1][0], EFC0, aE1, 0, 0, 0); \
        aO0 = __builtin_amdgcn_mfma_f32_16x16x32_f16(wh[0][1], EFC1, aO0, 0, 0, 0); \
        aO1 = __builtin_amdgcn_mfma_f32_16x16x32_f16(wh[1][1], EFC1, aO1, 0, 0, 0); \
        aE0 = __builtin_amdgcn_mfma_f32_16x16x32_f16(wh[0][2], EFC2, aE0, 0, 0, 0); \
        aE1 = __builtin_amdgcn_mfma_f32_16x16x32_f16(wh[1][2], EFC2, aE1, 0, 0, 0); \
        aO0 = __builtin_amdgcn_mfma_f32_16x16x32_f16(wh[0][3], EFC3, aO0, 0, 0, 0); \
        aO1 = __builtin_amdgcn_mfma_f32_16x16x32_f16(wh[1][3], EFC3, aO1, 0, 0, 0); \
        /* h MFMAs */                                                              \
        _Pragma("unroll")                                                          \
        for (int hb = 0; hb < 8; ++hb) {                                           \
            if (hb & 1) {                                                          \
                aO0 = __builtin_amdgcn_mfma_f32_16x16x32_f16(wh[0][hb + 4], ah[hb], aO0, 0, 0, 0); \
                aO1 = __builtin_amdgcn_mfma_f32_16x16x32_f16(wh[1][hb + 4], ah[hb], aO1, 0, 0, 0); \
            } else {                                                               \
                aE0 = __builtin_amdgcn_mfma_f32_16x16x32_f16(wh[0][hb + 4], ah[hb], aE0, 0, 0, 0); \
                aE1 = __builtin_amdgcn_mfma_f32_16x16x32_f16(wh[1][hb + 4], ah[hb], aE1, 0, 0, 0); \
            }                                                                      \
        }                                                                          \
        /* emb(t+1) fragments -> regs for next step (latency-tolerant) */          \
        EFN0 = *reinterpret_cast<const hfrag*>(SHb + 16384 + (ER) + ebr[0]);       \
        EFN1 = *reinterpret_cast<const hfrag*>(SHb + 16384 + (ER) + ebr[1]);       \
        EFN2 = *reinterpret_cast<const hfrag*>(SHb + 16384 + (ER) + ebr[2]);       \
        EFN3 = *reinterpret_cast<const hfrag*>(SHb + 16384 + (ER) + ebr[3]);       \
        /* stage emb(t+2) */                                                       \
        *reinterpret_cast<uint2*>(SHb + 16384 + (EW) + es) = EVS;                  \
        /* epilogue: lane holds h[m=col][n = ti*16 + 4q + r] */                    \
        _Pragma("unroll")                                                          \
        for (int i = 0; i < 2; ++i) {                                              \
            f4v s = (i == 0) ? (aE0 + aO0) : (aE1 + aO1);                          \
            float h0 = fast_tanh(s[0]), h1 = fast_tanh(s[1]);                      \
            float h2 = fast_tanh(s[2]), h3 = fast_tanh(s[3]);                      \
            uint2 hu = make_uint2(pk_h2(h0, h1), pk_h2(h2, h3));                   \
            *reinterpret_cast<uint2*>(SHb + wbyte[i] + (HW)) = hu;                 \
            if ((TT) == len_c - 1) snap[i] = hu;                                   \
        }                                                                          \
        asm volatile("s_waitcnt lgkmcnt(0)" ::: "memory");                         \
        __builtin_amdgcn_s_barrier();                                              \
        asm volatile("" ::: "memory");                                             \
    }

    // unroll x2: all parities are compile-time byte offsets.
    // odd tmax runs one harmless extra step (snap is exact-match guarded).
    #pragma unroll 1
    for (int t = 0; t < tmax; t += 2) {
        STEPX(0, 8192, 4096, 0, efA0,efA1,efA2,efA3, efB0,efB1,efB2,efB3, evA, evB, t)
        STEPX(8192, 0, 0, 4096, efB0,efB1,efB2,efB3, efA0,efA1,efA2,efA3, evB, evA, t + 1)
    }
#undef STEPX

    // ---- write last-h snapshots to LF (same swizzled fragment pattern) ----
    #pragma unroll
    for (int i = 0; i < 2; ++i) {
        const int ti = 2 * w + i;
        const int dl = ((ti & 1) * 2 + (q >> 1)) * 16 + col;
        *reinterpret_cast<uint2*>(&LF[SW((ti >> 1) * 256 + dl * 4 + (q & 1) * 2)]) = snap[i];
    }
    __syncthreads();

    // ---- fused FC1 (MFMA, f16 hi+lo) on LF ----
    f4v fH0, fH1, fL0, fL1;
    {
        float4 bb0 = *(const float4*)&b1[(2 * w) * 16 + 4 * q];
        float4 bb1 = *(const float4*)&b1[(2 * w + 1) * 16 + 4 * q];
        fH0 = (f4v){bb0.x, bb0.y, bb0.z, bb0.w};
        fH1 = (f4v){bb1.x, bb1.y, bb1.z, bb1.w};
        fL0 = zf; fL1 = zf;
    }
    #pragma unroll
    for (int kb = 0; kb < 8; ++kb) {
        hfrag ah = *reinterpret_cast<const hfrag*>(&LF[SW(kb * 256 + lane * 4)]);
        int fid0 = (kb * 16 + 2 * w) * 64 + lane;
        int fid1 = fid0 + 64;
        hfrag w0h = *reinterpret_cast<const hfrag*>(&wf1h[(size_t)fid0 * 4]);
        hfrag w1h = *reinterpret_cast<const hfrag*>(&wf1h[(size_t)fid1 * 4]);
        hfrag w0l = *reinterpret_cast<const hfrag*>(&wf1l[(size_t)fid0 * 4]);
        hfrag w1l = *reinterpret_cast<const hfrag*>(&wf1l[(size_t)fid1 * 4]);
        fH0 = __builtin_amdgcn_mfma_f32_16x16x32_f16(w0h, ah, fH0, 0, 0, 0);
        fH1 = __builtin_amdgcn_mfma_f32_16x16x32_f16(w1h, ah, fH1, 0, 0, 0);
        fL0 = __builtin_amdgcn_mfma_f32_16x16x32_f16(w0l, ah, fL0, 0, 0, 0);
        fL1 = __builtin_amdgcn_mfma_f32_16x16x32_f16(w1l, ah, fL1, 0, 0, 0);
    }

    // y = relu(...) into yb (aliases SH; step buffers dead, LF untouched)
    #pragma unroll
    for (int i = 0; i < 2; ++i) {
        int n0 = (2 * w + i) * 16 + 4 * q;
        f4v s = (i == 0) ? fH0 : fH1;
        f4v sl = (i == 0) ? fL0 : fL1;
        float4 yv;
        yv.x = fmaxf(s[0] + sl[0] * LO_DESCALE, 0.f);
        yv.y = fmaxf(s[1] + sl[1] * LO_DESCALE, 0.f);
        yv.z = fmaxf(s[2] + sl[2] * LO_DESCALE, 0.f);
        yv.w = fmaxf(s[3] + sl[3] * LO_DESCALE, 0.f);
        *reinterpret_cast<float4*>(&yb[col * 260 + n0]) = yv;
    }
    __syncthreads();

    // ---- FC2: 16 x 18 dots of length 256 ----
    if (tid < Mrows * Cv) {
        int r = tid & 15, cc = tid >> 4;
        float s = b2[cc];
        #pragma unroll 8
        for (int k4 = 0; k4 < Hv / 4; ++k4) {
            float4 yv = *reinterpret_cast<const float4*>(&yb[r * 260 + 4 * k4]);
            float4 wv2 = *(const float4*)&W2[cc * Hv + 4 * k4];
            s = fmaf(yv.x, wv2.x, s);
            s = fmaf(yv.y, wv2.y, s);
            s = fmaf(yv.z, wv2.z, s);
            s = fmaf(yv.w, wv2.w, s);
        }
        out[(rb + r) * Cv + cc] = s;
    }
}

extern "C" void kernel_launch(void* const* d_in, const int* in_sizes, int n_in,
                              void* d_out, int out_size, void* d_ws, size_t ws_size,
                              hipStream_t stream) {
    const int*   x_in  = (const int*)  d_in[0];
    const int*   x_len = (const int*)  d_in[1];
    const float* emb   = (const float*)d_in[2];
    const float* W_ih  = (const float*)d_in[3];
    const float* W_hh  = (const float*)d_in[4];
    const float* b_ih  = (const float*)d_in[5];
    const float* b_hh  = (const float*)d_in[6];
    const float* W1    = (const float*)d_in[7];
    const float* b1    = (const float*)d_in[8];
    const float* W2    = (const float*)d_in[9];
    const float* b2    = (const float*)d_in[10];
    float* out = (float*)d_out;

    unsigned* wfh    = (unsigned*)d_ws;          // 12288 frags * 16 B
    unsigned* wf1h   = wfh  + 12288 * 4;         // 8192 * 16 B
    unsigned* wf1l   = wf1h + 8192 * 4;          // 8192 * 16 B
    unsigned* emb16w = wf1l + 8192 * 4;          // 10000*128 f16 = 2.56 MB

    build_frags<<<705, 256, 0, stream>>>(W_ih, W_hh, W1, emb,
                                         wfh, wf1h, wf1l, emb16w);
    rnn_fused<<<Bv / Mrows, 512, 0, stream>>>(x_in, x_len,
                                              (const unsigned short*)emb16w,
                                              wfh, wf1h, wf1l, b_ih, b_hh,
                                              b1, W2, b2, out);
}

// Round 8
// 135.986 us; speedup vs baseline: 1.1648x; 1.0191x over previous
//
#include <hip/hip_runtime.h>
#include <hip/hip_fp16.h>
#include <math.h>

#define Bv 4096
#define Sv 64
#define Ev 128
#define Hv 256
#define Cv 18
#define Mrows 16

typedef _Float16 hfrag __attribute__((ext_vector_type(8)));
using f4v = __attribute__((ext_vector_type(4))) float;

#define LO_SCALE 2048.0f            // 2^11 on w1_lo (FC1 only)
#define LO_DESCALE (1.0f / 2048.0f)

// XOR swizzle: flips bits 2-4 by a hash of higher bits. Bits 0-1 preserved
// -> b64/b128 contiguity kept. Applied to buffer-relative WORD offsets;
// write and read sides use the same mapping (bijective per 2048-word region).
__device__ inline int SW(int o) {
    return o ^ ((((o >> 5) ^ (o >> 8)) & 7) << 2);
}

__device__ inline float fast_tanh(float x) {
    // tanh(x) = 1 - 2/(exp2(2x*log2e)+1)
    float e = __builtin_amdgcn_exp2f(x * 2.8853900817779268f);
    return 1.0f - 2.0f * __builtin_amdgcn_rcpf(e + 1.0f);
}

__device__ inline unsigned pk_h2(float a, float b) {
    unsigned ua = __half_as_ushort(__float2half_rn(a));
    unsigned ub = __half_as_ushort(__float2half_rn(b));
    return ua | (ub << 16);
}

// ---- kernel A: build MFMA weight fragments + f16 embedding table ----
__global__ void build_frags(const float* __restrict__ W_ih,
                            const float* __restrict__ W_hh,
                            const float* __restrict__ W1,
                            const float* __restrict__ emb,
                            unsigned* __restrict__ wfh,
                            unsigned* __restrict__ wf1h, unsigned* __restrict__ wf1l,
                            unsigned* __restrict__ emb16w) {
    if (blockIdx.x >= 80) {
        int i = (blockIdx.x - 80) * 256 + threadIdx.x;   // 0..159999
        float4 a = *(const float4*)&emb[(size_t)i * 8];
        float4 b = *(const float4*)&emb[(size_t)i * 8 + 4];
        uint4 o;
        o.x = pk_h2(a.x, a.y); o.y = pk_h2(a.z, a.w);
        o.z = pk_h2(b.x, b.y); o.w = pk_h2(b.z, b.w);
        *reinterpret_cast<uint4*>(&emb16w[(size_t)i * 4]) = o;
        return;
    }
    int f = blockIdx.x * 256 + threadIdx.x;   // 0..20479
    bool isrnn = f < 12288;
    int g = isrnn ? f : f - 12288;
    int lane = g & 63, tile = (g >> 6) & 15, kb = g >> 10;
    int q = lane >> 4, col = lane & 15;
    int n = tile * 16 + col;
    unsigned hu[8], lu[8];
    #pragma unroll
    for (int j = 0; j < 8; ++j) {
        int k = kb * 32 + q * 8 + j;
        float x;
        if (isrnn) x = (k < Ev) ? W_ih[n * Ev + k] : W_hh[n * Hv + (k - Ev)];
        else       x = W1[n * Hv + k];
        __half h = __float2half_rn(x);
        hu[j] = __half_as_ushort(h);
        float l = (x - __half2float(h)) * LO_SCALE;
        lu[j] = __half_as_ushort(__float2half_rn(l));
    }
    unsigned* oh = (isrnn ? wfh : wf1h) + (size_t)g * 4;
    #pragma unroll
    for (int d = 0; d < 4; ++d) oh[d] = hu[2 * d] | (hu[2 * d + 1] << 16);
    if (!isrnn) {
        unsigned* ol = wf1l + (size_t)g * 4;
        #pragma unroll
        for (int d = 0; d < 4; ++d) ol[d] = lu[2 * d] | (lu[2 * d + 1] << 16);
    }
}

// ---- kernel B: fused recurrence + FC head; 8 waves x 2 N-tiles ----
// vs R7: the input-projection MFMAs for step t+1 (4 emb kbs x 2 tiles) are
// hoisted PRE-barrier: EFN ds_reads issue at step start, and the 8 MFMAs
// re-initialize the accumulators between the merge and the tanh -> the
// matrix pipe fills the epilogue's idle window; post-barrier burst is 16
// MFMAs. Unconditional (prologue pre-accumulates b + xW(0)); accumulators
// live across the barrier in registers. sched_barrier(0) pins the hoisted
// MFMAs above the raw barrier (reg-only MFMAs ignore "memory" clobber).
// LDS map (bytes): h dbuf 0/8192 (8 kb x 1 KB each); emb dbuf 16384 + 0/4096.
__global__ __launch_bounds__(512, 2) void rnn_fused(
    const int* __restrict__ x_in, const int* __restrict__ x_len,
    const unsigned short* __restrict__ emb16,
    const unsigned* __restrict__ wfh,
    const unsigned* __restrict__ wf1h, const unsigned* __restrict__ wf1l,
    const float* __restrict__ b_ih, const float* __restrict__ b_hh,
    const float* __restrict__ b1, const float* __restrict__ W2,
    const float* __restrict__ b2, float* __restrict__ out)
{
    __shared__ unsigned SH[6144];   // 24 KB: h dbuf (0..4095) + emb dbuf (4096..6143)
    __shared__ unsigned LF[2048];   // 8 KB last-h fragments
    float* yb = reinterpret_cast<float*>(SH);   // fc y buffer aliases SH after loop
    char* SHb = reinterpret_cast<char*>(SH);

    const int tid = threadIdx.x;
    const int lane = tid & 63, w = tid >> 6;     // wave 0..7
    const int q = lane >> 4, col = lane & 15;
    const int rb = blockIdx.x * Mrows;

    // resident W: tiles 2w, 2w+1 -> f16 hi all 12 kb (96 regs)
    hfrag wh[2][12];
    #pragma unroll
    for (int i = 0; i < 2; ++i) {
        const int ti = 2 * w + i;
        #pragma unroll
        for (int kb = 0; kb < 12; ++kb) {
            int fid = (kb * 16 + ti) * 64 + lane;
            wh[i][kb] = *reinterpret_cast<const hfrag*>(&wfh[(size_t)fid * 4]);
        }
    }
    #pragma unroll
    for (int i = 0; i < 2; ++i)
        #pragma unroll
        for (int kb = 0; kb < 12; ++kb) asm volatile("" : "+v"(wh[i][kb]));

    // bias folded into MFMA C-init of the even chains
    f4v bcv0, bcv1;
    #pragma unroll
    for (int r = 0; r < 4; ++r) {
        bcv0[r] = b_ih[(2 * w) * 16 + 4 * q + r] + b_hh[(2 * w) * 16 + 4 * q + r];
        bcv1[r] = b_ih[(2 * w + 1) * 16 + 4 * q + r] + b_hh[(2 * w + 1) * 16 + 4 * q + r];
    }
    const int len_c = x_len[rb + col];
    int tmax = len_c;
    #pragma unroll
    for (int m = 1; m < 16; m <<= 1) {
        int o = __shfl_xor(tmax, m, 64);
        tmax = tmax > o ? tmax : o;
    }

    // precomputed swizzled LDS BYTE offsets (loop-invariant registers)
    int hbyte[8];                       // h A-fragment reads, h-kb 0..7
    #pragma unroll
    for (int hb = 0; hb < 8; ++hb) hbyte[hb] = SW(hb * 256 + lane * 4) * 4;
    int ebr[4];                         // emb A-fragment reads, kb 0..3
    #pragma unroll
    for (int kb = 0; kb < 4; ++kb) ebr[kb] = SW(kb * 256 + lane * 4) * 4;
    int wbyte[2];                       // h-fragment writes (2 tiles)
    #pragma unroll
    for (int i = 0; i < 2; ++i) {
        const int ti = 2 * w + i;
        const int dl = ((ti & 1) * 2 + (q >> 1)) * 16 + col;
        wbyte[i] = SW((ti >> 1) * 256 + dl * 4 + (q & 1) * 2) * 4;
    }
    // emb staging: thread = (row em, 8B-chunk kt): copies 8 B (4 halves)
    const int em = tid >> 5;            // row 0..15
    const int kt = tid & 31;            // 8B chunk 0..31
    const int es = SW((kt >> 3) * 256 + (((kt >> 1) & 3) * 16 + em) * 4 + (kt & 1) * 2) * 4;
    const int* xrow = x_in + (size_t)(rb + em) * Sv;
    const char* embB = reinterpret_cast<const char*>(emb16);
    const int ekoff = kt * 8;           // byte offset within 256 B emb16 row

    // zero h buffer 0 (bytes 0..8191)
    for (int u = tid; u < 2048; u += 512) SH[u] = 0u;

    // prologue: stage emb(0)->ebuf0, emb(1)->ebuf1; evA = row 2
    {
        uint2 e0 = *reinterpret_cast<const uint2*>(embB + ((unsigned)xrow[0] << 8) + ekoff);
        uint2 e1 = *reinterpret_cast<const uint2*>(embB + ((unsigned)xrow[1] << 8) + ekoff);
        *reinterpret_cast<uint2*>(SHb + 16384 + es) = e0;
        *reinterpret_cast<uint2*>(SHb + 16384 + 4096 + es) = e1;
    }
    uint2 evA = *reinterpret_cast<const uint2*>(embB + ((unsigned)xrow[2] << 8) + ekoff);
    uint2 evB;
    uint2 snap[2];
    snap[0] = snap[1] = make_uint2(0u, 0u);
    __syncthreads();

    f4v zf = {0.f, 0.f, 0.f, 0.f};

    // pre-loop: read emb(0) fragments and pre-accumulate b + xW(0) into the
    // live accumulators; second barrier so all waves' ebuf0 reads complete
    // before step 0 overwrites it with emb(2).
    f4v aE0, aE1, aO0, aO1;
    {
        hfrag ef0 = *reinterpret_cast<const hfrag*>(SHb + 16384 + ebr[0]);
        hfrag ef1 = *reinterpret_cast<const hfrag*>(SHb + 16384 + ebr[1]);
        hfrag ef2 = *reinterpret_cast<const hfrag*>(SHb + 16384 + ebr[2]);
        hfrag ef3 = *reinterpret_cast<const hfrag*>(SHb + 16384 + ebr[3]);
        aE0 = __builtin_amdgcn_mfma_f32_16x16x32_f16(wh[0][0], ef0, bcv0, 0, 0, 0);
        aE1 = __builtin_amdgcn_mfma_f32_16x16x32_f16(wh[1][0], ef0, bcv1, 0, 0, 0);
        aO0 = __builtin_amdgcn_mfma_f32_16x16x32_f16(wh[0][1], ef1, zf, 0, 0, 0);
        aO1 = __builtin_amdgcn_mfma_f32_16x16x32_f16(wh[1][1], ef1, zf, 0, 0, 0);
        aE0 = __builtin_amdgcn_mfma_f32_16x16x32_f16(wh[0][2], ef2, aE0, 0, 0, 0);
        aE1 = __builtin_amdgcn_mfma_f32_16x16x32_f16(wh[1][2], ef2, aE1, 0, 0, 0);
        aO0 = __builtin_amdgcn_mfma_f32_16x16x32_f16(wh[0][3], ef3, aO0, 0, 0, 0);
        aO1 = __builtin_amdgcn_mfma_f32_16x16x32_f16(wh[1][3], ef3, aO1, 0, 0, 0);
    }
    __syncthreads();

    // One step t: acc already holds b + xW(t). Read h(t-1) at parity HR,
    // 16 h-MFMAs; read emb(t+1) frags from ER and re-init acc for t+1
    // (8 emb MFMAs, pre-barrier, overlapping the tanh VALU); stage emb(t+2)
    // =EVS to EW; write h(t) at HW; EVL = global load row t+3.
#define STEPX(HR, HW, ER, EW, EVS, EVL, TT)                                        \
    {                                                                              \
        int tn = (TT) + 3; tn = tn > 63 ? 63 : tn;                                 \
        EVL = *reinterpret_cast<const uint2*>(embB + ((unsigned)xrow[tn] << 8) + ekoff); \
        hfrag ah[8];                                                               \
        _Pragma("unroll")                                                          \
        for (int hb = 0; hb < 8; ++hb)                                             \
            ah[hb] = *reinterpret_cast<const hfrag*>(SHb + hbyte[hb] + (HR));      \
        hfrag efn0 = *reinterpret_cast<const hfrag*>(SHb + 16384 + (ER) + ebr[0]); \
        hfrag efn1 = *reinterpret_cast<const hfrag*>(SHb + 16384 + (ER) + ebr[1]); \
        hfrag efn2 = *reinterpret_cast<const hfrag*>(SHb + 16384 + (ER) + ebr[2]); \
        hfrag efn3 = *reinterpret_cast<const hfrag*>(SHb + 16384 + (ER) + ebr[3]); \
        /* h MFMAs (post-barrier critical burst: 16) */                            \
        _Pragma("unroll")                                                          \
        for (int hb = 0; hb < 8; ++hb) {                                           \
            if (hb & 1) {                                                          \
                aO0 = __builtin_amdgcn_mfma_f32_16x16x32_f16(wh[0][hb + 4], ah[hb], aO0, 0, 0, 0); \
                aO1 = __builtin_amdgcn_mfma_f32_16x16x32_f16(wh[1][hb + 4], ah[hb], aO1, 0, 0, 0); \
            } else {                                                               \
                aE0 = __builtin_amdgcn_mfma_f32_16x16x32_f16(wh[0][hb + 4], ah[hb], aE0, 0, 0, 0); \
                aE1 = __builtin_amdgcn_mfma_f32_16x16x32_f16(wh[1][hb + 4], ah[hb], aE1, 0, 0, 0); \
            }                                                                      \
        }                                                                          \
        /* stage emb(t+2) */                                                       \
        *reinterpret_cast<uint2*>(SHb + 16384 + (EW) + es) = EVS;                  \
        /* merge; acc regs now free for t+1 */                                     \
        f4v s0 = aE0 + aO0, s1 = aE1 + aO1;                                        \
        /* input projection for t+1: MFMA pipe runs under the tanh below */        \
        aE0 = __builtin_amdgcn_mfma_f32_16x16x32_f16(wh[0][0], efn0, bcv0, 0, 0, 0); \
        aE1 = __builtin_amdgcn_mfma_f32_16x16x32_f16(wh[1][0], efn0, bcv1, 0, 0, 0); \
        aO0 = __builtin_amdgcn_mfma_f32_16x16x32_f16(wh[0][1], efn1, zf, 0, 0, 0); \
        aO1 = __builtin_amdgcn_mfma_f32_16x16x32_f16(wh[1][1], efn1, zf, 0, 0, 0); \
        aE0 = __builtin_amdgcn_mfma_f32_16x16x32_f16(wh[0][2], efn2, aE0, 0, 0, 0); \
        aE1 = __builtin_amdgcn_mfma_f32_16x16x32_f16(wh[1][2], efn2, aE1, 0, 0, 0); \
        aO0 = __builtin_amdgcn_mfma_f32_16x16x32_f16(wh[0][3], efn3, aO0, 0, 0, 0); \
        aO1 = __builtin_amdgcn_mfma_f32_16x16x32_f16(wh[1][3], efn3, aO1, 0, 0, 0); \
        /* epilogue: lane holds h[m=col][n = ti*16 + 4q + r] */                    \
        {                                                                          \
            float h0 = fast_tanh(s0[0]), h1 = fast_tanh(s0[1]);                    \
            float h2 = fast_tanh(s0[2]), h3 = fast_tanh(s0[3]);                    \
            uint2 hu = make_uint2(pk_h2(h0, h1), pk_h2(h2, h3));                   \
            *reinterpret_cast<uint2*>(SHb + wbyte[0] + (HW)) = hu;                 \
            if ((TT) == len_c - 1) snap[0] = hu;                                   \
        }                                                                          \
        {                                                                          \
            float h0 = fast_tanh(s1[0]), h1 = fast_tanh(s1[1]);                    \
            float h2 = fast_tanh(s1[2]), h3 = fast_tanh(s1[3]);                    \
            uint2 hu = make_uint2(pk_h2(h0, h1), pk_h2(h2, h3));                   \
            *reinterpret_cast<uint2*>(SHb + wbyte[1] + (HW)) = hu;                 \
            if ((TT) == len_c - 1) snap[1] = hu;                                   \
        }                                                                          \
        __builtin_amdgcn_sched_barrier(0);                                         \
        asm volatile("s_waitcnt lgkmcnt(0)" ::: "memory");                         \
        __builtin_amdgcn_s_barrier();                                              \
        asm volatile("" ::: "memory");                                             \
    }

    // unroll x2: all parities are compile-time byte offsets.
    // odd tmax runs one harmless extra step (snap is exact-match guarded).
    #pragma unroll 1
    for (int t = 0; t < tmax; t += 2) {
        STEPX(0, 8192, 4096, 0, evA, evB, t)
        STEPX(8192, 0, 0, 4096, evB, evA, t + 1)
    }
#undef STEPX

    // ---- write last-h snapshots to LF (same swizzled fragment pattern) ----
    #pragma unroll
    for (int i = 0; i < 2; ++i) {
        const int ti = 2 * w + i;
        const int dl = ((ti & 1) * 2 + (q >> 1)) * 16 + col;
        *reinterpret_cast<uint2*>(&LF[SW((ti >> 1) * 256 + dl * 4 + (q & 1) * 2)]) = snap[i];
    }
    __syncthreads();

    // ---- fused FC1 (MFMA, f16 hi+lo) on LF ----
    f4v fH0, fH1, fL0, fL1;
    {
        float4 bb0 = *(const float4*)&b1[(2 * w) * 16 + 4 * q];
        float4 bb1 = *(const float4*)&b1[(2 * w + 1) * 16 + 4 * q];
        fH0 = (f4v){bb0.x, bb0.y, bb0.z, bb0.w};
        fH1 = (f4v){bb1.x, bb1.y, bb1.z, bb1.w};
        fL0 = zf; fL1 = zf;
    }
    #pragma unroll
    for (int kb = 0; kb < 8; ++kb) {
        hfrag ah = *reinterpret_cast<const hfrag*>(&LF[SW(kb * 256 + lane * 4)]);
        int fid0 = (kb * 16 + 2 * w) * 64 + lane;
        int fid1 = fid0 + 64;
        hfrag w0h = *reinterpret_cast<const hfrag*>(&wf1h[(size_t)fid0 * 4]);
        hfrag w1h = *reinterpret_cast<const hfrag*>(&wf1h[(size_t)fid1 * 4]);
        hfrag w0l = *reinterpret_cast<const hfrag*>(&wf1l[(size_t)fid0 * 4]);
        hfrag w1l = *reinterpret_cast<const hfrag*>(&wf1l[(size_t)fid1 * 4]);
        fH0 = __builtin_amdgcn_mfma_f32_16x16x32_f16(w0h, ah, fH0, 0, 0, 0);
        fH1 = __builtin_amdgcn_mfma_f32_16x16x32_f16(w1h, ah, fH1, 0, 0, 0);
        fL0 = __builtin_amdgcn_mfma_f32_16x16x32_f16(w0l, ah, fL0, 0, 0, 0);
        fL1 = __builtin_amdgcn_mfma_f32_16x16x32_f16(w1l, ah, fL1, 0, 0, 0);
    }

    // y = relu(...) into yb (aliases SH; step buffers dead, LF untouched)
    #pragma unroll
    for (int i = 0; i < 2; ++i) {
        int n0 = (2 * w + i) * 16 + 4 * q;
        f4v s = (i == 0) ? fH0 : fH1;
        f4v sl = (i == 0) ? fL0 : fL1;
        float4 yv;
        yv.x = fmaxf(s[0] + sl[0] * LO_DESCALE, 0.f);
        yv.y = fmaxf(s[1] + sl[1] * LO_DESCALE, 0.f);
        yv.z = fmaxf(s[2] + sl[2] * LO_DESCALE, 0.f);
        yv.w = fmaxf(s[3] + sl[3] * LO_DESCALE, 0.f);
        *reinterpret_cast<float4*>(&yb[col * 260 + n0]) = yv;
    }
    __syncthreads();

    // ---- FC2: 16 x 18 dots of length 256 ----
    if (tid < Mrows * Cv) {
        int r = tid & 15, cc = tid >> 4;
        float s = b2[cc];
        #pragma unroll 8
        for (int k4 = 0; k4 < Hv / 4; ++k4) {
            float4 yv = *reinterpret_cast<const float4*>(&yb[r * 260 + 4 * k4]);
            float4 wv2 = *(const float4*)&W2[cc * Hv + 4 * k4];
            s = fmaf(yv.x, wv2.x, s);
            s = fmaf(yv.y, wv2.y, s);
            s = fmaf(yv.z, wv2.z, s);
            s = fmaf(yv.w, wv2.w, s);
        }
        out[(rb + r) * Cv + cc] = s;
    }
}

extern "C" void kernel_launch(void* const* d_in, const int* in_sizes, int n_in,
                              void* d_out, int out_size, void* d_ws, size_t ws_size,
                              hipStream_t stream) {
    const int*   x_in  = (const int*)  d_in[0];
    const int*   x_len = (const int*)  d_in[1];
    const float* emb   = (const float*)d_in[2];
    const float* W_ih  = (const float*)d_in[3];
    const float* W_hh  = (const float*)d_in[4];
    const float* b_ih  = (const float*)d_in[5];
    const float* b_hh  = (const float*)d_in[6];
    const float* W1    = (const float*)d_in[7];
    const float* b1    = (const float*)d_in[8];
    const float* W2    = (const float*)d_in[9];
    const float* b2    = (const float*)d_in[10];
    float* out = (float*)d_out;

    unsigned* wfh    = (unsigned*)d_ws;          // 12288 frags * 16 B
    unsigned* wf1h   = wfh  + 12288 * 4;         // 8192 * 16 B
    unsigned* wf1l   = wf1h + 8192 * 4;          // 8192 * 16 B
    unsigned* emb16w = wf1l + 8192 * 4;          // 10000*128 f16 = 2.56 MB

    build_frags<<<705, 256, 0, stream>>>(W_ih, W_hh, W1, emb,
                                         wfh, wf1h, wf1l, emb16w);
    rnn_fused<<<Bv / Mrows, 512, 0, stream>>>(x_in, x_len,
                                              (const unsigned short*)emb16w,
                                              wfh, wf1h, wf1l, b_ih, b_hh,
                                              b1, W2, b2, out);
}